// Round 8
// baseline (161.366 us; speedup 1.0000x reference)
//
#include <hip/hip_runtime.h>

#define B_ 8
#define L_ 1024
#define H_ 8
#define DM_ 640

typedef __attribute__((ext_vector_type(8))) short bf16x8;
typedef __attribute__((ext_vector_type(4))) short bf16x4;
typedef __attribute__((ext_vector_type(4))) float f32x4;
typedef __attribute__((ext_vector_type(2))) float f32x2;
typedef __attribute__((ext_vector_type(2))) int i32x2;
typedef __attribute__((ext_vector_type(4))) unsigned short us4;
typedef __attribute__((ext_vector_type(8))) unsigned short us8;

#if __has_builtin(__builtin_amdgcn_exp2f)
#define EXP2F __builtin_amdgcn_exp2f
#else
#define EXP2F exp2f
#endif

#define C1F 0.22195308f  // 2*log2(e)/13
#define C2F 0.11097654f  // log2(e)/13

// d_out: [0, 10616832)           Vtp fragment-major V' tiles: per (bh,kt) 10368B =
//                                20x512B frags [u][t][col][g][e0..3] (= w'*V^T) + 128B w' row
//        [10616832, 15859712)    attn fp8 e4m3 [8192][640]
//        [15859712, 16269312)    Wf8 fragment-major fp8 W: 800 chunks [jt][kc][col][g][e0..7]
//        (ln overwrites d_out with y at the end)
// ws:    [0, 10485760)           Kp fragment-major bf16(K*C1): per (bh,kt) 10240B =
//                                [t]{c0:1KB,c1:1KB,c2:512B} [col][g][e0..7]; c2 = dims 64..79
//        (fc overwrites ws with x bf16; attn done by then)
#define KP_TILE_SHORTS 5120
#define VTP_TILE_SHORTS 5184
#define ATTN8_OFF 10616832
#define WF8_OFF 15859712

__device__ __forceinline__ unsigned short f2bf(float f) {
  unsigned int u = __builtin_bit_cast(unsigned int, f);
  u += 0x7fffu + ((u >> 16) & 1u);
  return (unsigned short)(u >> 16);
}
__device__ __forceinline__ float bf2f(unsigned short h) {
  unsigned int u = ((unsigned int)h) << 16;
  return __builtin_bit_cast(float, u);
}
__device__ __forceinline__ float sane(float x, float lim) {
  return fminf(fmaxf(x, -lim), lim);  // also maps NaN -> -lim
}
__device__ __forceinline__ unsigned cvt_pk_bf16(float a, float b) {
  unsigned r;
  asm("v_cvt_pk_bf16_f32 %0, %1, %2" : "=v"(r) : "v"(a), "v"(b));
  return r;
}

// -------------------- Kernel W: W fp32 -> fp8 fragment-major --------------------
__global__ __launch_bounds__(256) void wcvt_kernel(const float* __restrict__ w,
                                                   unsigned char* __restrict__ wf8) {
  const int idx = blockIdx.x * 256 + threadIdx.x;  // [0, 102400) dwords
  const int chunk = idx >> 7, r = idx & 127;
  const int jt = chunk / 20, kc = chunk - jt * 20;
  const int colx = r >> 3, gx = (r >> 1) & 3, eh = r & 1;
  const float* src = w + (size_t)(jt * 16 + colx) * DM_ + kc * 32 + gx * 8 + eh * 4;
  float4 f = *(const float4*)src;
  int pk = __builtin_amdgcn_cvt_pk_fp8_f32(f.x, f.y, 0, false);
  pk = __builtin_amdgcn_cvt_pk_fp8_f32(f.z, f.w, pk, true);
  *(int*)(wf8 + (size_t)idx * 4) = pk;
}

// -------------------- Kernel 0: prep (fragment-major K', V', w') --------------------
__global__ __launch_bounds__(256) void prep_kernel(
    const float* __restrict__ kg, const float* __restrict__ vg,
    unsigned short* __restrict__ Kp, unsigned short* __restrict__ Vtp) {
  __shared__ float V_lds[64 * 81];
  __shared__ __align__(16) unsigned short K_lds2[64 * 80];
  __shared__ float w_lds[64];
  const int tid = threadIdx.x;
  const int bh = blockIdx.x >> 4, kt = blockIdx.x & 15;
  const int b = bh >> 3, h = bh & 7;
  const int key = tid >> 2, part = tid & 3;
  const int keyg = kt * 64 + key;

  const float* krow = kg + (size_t)(b * L_ + keyg) * DM_ + h * 80 + part * 20;
  const float* vrow = vg + (size_t)(b * L_ + keyg) * DM_ + h * 80 + part * 20;

  float ssq = 0.f;
#pragma unroll
  for (int i = 0; i < 5; ++i) {
    float4 f = *(const float4*)(krow + 4 * i);
    ssq += f.x * f.x + f.y * f.y + f.z * f.z + f.w * f.w;
    us4 h4 = {f2bf(f.x * C1F), f2bf(f.y * C1F), f2bf(f.z * C1F), f2bf(f.w * C1F)};
    *(us4*)&K_lds2[key * 80 + part * 20 + 4 * i] = h4;
    float4 g4 = *(const float4*)(vrow + 4 * i);
    int d0 = part * 20 + 4 * i;
    V_lds[key * 81 + d0 + 0] = g4.x;
    V_lds[key * 81 + d0 + 1] = g4.y;
    V_lds[key * 81 + d0 + 2] = g4.z;
    V_lds[key * 81 + d0 + 3] = g4.w;
  }
  ssq += __shfl_xor(ssq, 1);
  ssq += __shfl_xor(ssq, 2);
  if (part == 0) w_lds[key] = EXP2F((80.f - ssq) * C2F);
  __syncthreads();

  // Kp fragments: 640 us8 chunks; chunk f -> (t, c, col, g); dst = f*8 shorts
  unsigned short* kdst = Kp + (size_t)(bh * 16 + kt) * KP_TILE_SHORTS;
#pragma unroll
  for (int rnd = 0; rnd < 3; ++rnd) {
    int f = rnd * 256 + tid;
    if (f < 640) {
      int t = f / 160, r = f - t * 160;
      int srcoff;
      if (r < 128) {
        int c = r >> 6, rr = r & 63;
        srcoff = (t * 16 + (rr >> 2)) * 80 + c * 32 + (rr & 3) * 8;
      } else {
        int rr = r - 128;
        srcoff = (t * 16 + (rr >> 1)) * 80 + 64 + (rr & 1) * 8;
      }
      *(us8*)(kdst + f * 8) = *(const us8*)&K_lds2[srcoff];
    }
  }

  // Vtp fragments: 1280 us4 chunks [u][t][col][g][e0..3] + 64-short w' row
  unsigned short* vdst = Vtp + (size_t)(bh * 16 + kt) * VTP_TILE_SHORTS;
#pragma unroll
  for (int rnd = 0; rnd < 5; ++rnd) {
    int idx = rnd * 256 + tid;
    int ut = idx >> 6, r = idx & 63;
    int u = ut >> 2, t = ut & 3, colx = r >> 2, gx = r & 3;
    int dv = u * 16 + colx, k0 = t * 16 + gx * 4;
    us4 o = {f2bf(V_lds[k0 * 81 + dv] * w_lds[k0]),
             f2bf(V_lds[(k0 + 1) * 81 + dv] * w_lds[k0 + 1]),
             f2bf(V_lds[(k0 + 2) * 81 + dv] * w_lds[k0 + 2]),
             f2bf(V_lds[(k0 + 3) * 81 + dv] * w_lds[k0 + 3])};
    *(us4*)(vdst + idx * 4) = o;
  }
  if (tid < 16) {
    int k0 = tid * 4;
    us4 o = {f2bf(w_lds[k0]), f2bf(w_lds[k0 + 1]), f2bf(w_lds[k0 + 2]),
             f2bf(w_lds[k0 + 3])};
    *(us4*)(vdst + 5120 + tid * 4) = o;
  }
}

// -------------------- Kernel A: flash attention, NO LDS, NO barriers --------------------
// All operand fragments loaded straight from L2-resident fragment-major tiles.
// Swapped QK^T: lane(col=q,g) holds S[key=t*16+g*4+reg][q]; p = exp2(S) (bounded);
// PV via 16x16x16 MFMA; l = in-register dot  sum_k w'_k * p_k  (f32) + 2 shfl at end.
__global__ __launch_bounds__(256, 2) void attn_kernel(
    const float* __restrict__ qg, const unsigned short* __restrict__ Kp,
    const unsigned short* __restrict__ Vtp, unsigned char* __restrict__ attn8) {
  const int tid = threadIdx.x;
  const int wid = tid >> 6, lane = tid & 63;
  const int col = lane & 15, g = lane >> 4;
  const int bx = blockIdx.x;
  const int bh = bx & 63, qt = bx >> 6;  // same-bh blocks land 64 apart -> same XCD slot
  const int b = bh >> 3, h = bh & 7;

  const int koff01 = col * 32 + g * 8;        // shorts, c<2 fragments
  const int koff2 = 1024 + col * 16 + g * 8;  // shorts, c==2 (g<2 only)
  const int voff = col * 16 + g * 4;          // shorts, V fragments
  const int woff = 5120 + g * 4;              // shorts, w' row (+ t*16)

  // Q fragments for the two subtiles (B-operand: lane col = q-row, dims g*8+e)
  bf16x8 qa0[3], qa1[3];
  {
    const int qr0 = qt * 128 + wid * 16 + col;
#pragma unroll
    for (int s = 0; s < 2; ++s) {
      const float* qr = qg + (size_t)(b * L_ + qr0 + s * 64) * DM_ + h * 80;
      bf16x8* qa = s ? qa1 : qa0;
#pragma unroll
      for (int c = 0; c < 3; ++c) {
        int d0 = c * 32 + g * 8;
        if (d0 < 80) {
          float4 f0 = *(const float4*)(qr + d0);
          float4 f1 = *(const float4*)(qr + d0 + 4);
          qa[c][0] = (short)f2bf(f0.x); qa[c][1] = (short)f2bf(f0.y);
          qa[c][2] = (short)f2bf(f0.z); qa[c][3] = (short)f2bf(f0.w);
          qa[c][4] = (short)f2bf(f1.x); qa[c][5] = (short)f2bf(f1.y);
          qa[c][6] = (short)f2bf(f1.z); qa[c][7] = (short)f2bf(f1.w);
        } else {
#pragma unroll
          for (int e = 0; e < 8; ++e) qa[c][e] = 0;
        }
      }
    }
  }

  f32x4 acc_o0[5], acc_o1[5];
#pragma unroll
  for (int u = 0; u < 5; ++u) {
    f32x4 z = {0.f, 0.f, 0.f, 0.f};
    acc_o0[u] = z;
    acc_o1[u] = z;
  }
  float lp0 = 0.f, lp1 = 0.f;

  const unsigned short* kb = Kp + (size_t)(bh * 16) * KP_TILE_SHORTS;
  const unsigned short* vb = Vtp + (size_t)(bh * 16) * VTP_TILE_SHORTS;

  for (int kt = 0; kt < 16; ++kt) {
    const unsigned short* kk = kb + (size_t)kt * KP_TILE_SHORTS;
    const unsigned short* vv = vb + (size_t)kt * VTP_TILE_SHORTS;

    // QK^T
    f32x4 accS0[4], accS1[4];
#pragma unroll
    for (int t = 0; t < 4; ++t) {
      f32x4 z = {0.f, 0.f, 0.f, 0.f};
      accS0[t] = z;
      accS1[t] = z;
    }
#pragma unroll
    for (int t = 0; t < 4; ++t) {
      const unsigned short* tb = kk + t * 1280;
      bf16x8 k0 = *(const bf16x8*)(tb + koff01);
      bf16x8 k1 = *(const bf16x8*)(tb + 512 + koff01);
      bf16x8 k2 = {0, 0, 0, 0, 0, 0, 0, 0};
      if (g < 2) k2 = *(const bf16x8*)(tb + koff2);
      accS0[t] = __builtin_amdgcn_mfma_f32_16x16x32_bf16(k0, qa0[0], accS0[t], 0, 0, 0);
      accS1[t] = __builtin_amdgcn_mfma_f32_16x16x32_bf16(k0, qa1[0], accS1[t], 0, 0, 0);
      accS0[t] = __builtin_amdgcn_mfma_f32_16x16x32_bf16(k1, qa0[1], accS0[t], 0, 0, 0);
      accS1[t] = __builtin_amdgcn_mfma_f32_16x16x32_bf16(k1, qa1[1], accS1[t], 0, 0, 0);
      accS0[t] = __builtin_amdgcn_mfma_f32_16x16x32_bf16(k2, qa0[2], accS0[t], 0, 0, 0);
      accS1[t] = __builtin_amdgcn_mfma_f32_16x16x32_bf16(k2, qa1[2], accS1[t], 0, 0, 0);
    }

    // softmax numerators + l-dot + PV
#pragma unroll
    for (int t = 0; t < 4; ++t) {
      us4 w4 = *(const us4*)(vv + woff + t * 16);
      float w0 = bf2f(w4[0]), w1 = bf2f(w4[1]), w2 = bf2f(w4[2]), w3 = bf2f(w4[3]);
      float p00 = EXP2F(accS0[t][0]), p01 = EXP2F(accS0[t][1]);
      float p02 = EXP2F(accS0[t][2]), p03 = EXP2F(accS0[t][3]);
      float p10 = EXP2F(accS1[t][0]), p11 = EXP2F(accS1[t][1]);
      float p12 = EXP2F(accS1[t][2]), p13 = EXP2F(accS1[t][3]);
      lp0 += p00 * w0 + p01 * w1 + p02 * w2 + p03 * w3;
      lp1 += p10 * w0 + p11 * w1 + p12 * w2 + p13 * w3;
      i32x2 pw0 = {(int)cvt_pk_bf16(p00, p01), (int)cvt_pk_bf16(p02, p03)};
      i32x2 pw1 = {(int)cvt_pk_bf16(p10, p11), (int)cvt_pk_bf16(p12, p13)};
      bf16x4 pf0 = __builtin_bit_cast(bf16x4, pw0);
      bf16x4 pf1 = __builtin_bit_cast(bf16x4, pw1);
#pragma unroll
      for (int u = 0; u < 5; ++u) {
        bf16x4 vf = *(const bf16x4*)(vv + (u * 4 + t) * 256 + voff);
        acc_o0[u] = __builtin_amdgcn_mfma_f32_16x16x16bf16_1k(vf, pf0, acc_o0[u], 0, 0, 0);
        acc_o1[u] = __builtin_amdgcn_mfma_f32_16x16x16bf16_1k(vf, pf1, acc_o1[u], 0, 0, 0);
      }
    }
  }

  // l = cross-g reduce of lp (all terms positive -> l > 0); fp8 output
  float l0 = lp0 + __shfl_xor(lp0, 16);
  l0 += __shfl_xor(l0, 32);
  float l1 = lp1 + __shfl_xor(lp1, 16);
  l1 += __shfl_xor(l1, 32);
#pragma unroll
  for (int s = 0; s < 2; ++s) {
    f32x4* acc_o = s ? acc_o1 : acc_o0;
    float invl = 1.0f / fmaxf(s ? l1 : l0, 1e-30f);
    const int qrow = qt * 128 + s * 64 + wid * 16 + col;
    unsigned char* ob = attn8 + (size_t)(b * L_ + qrow) * DM_ + h * 80;
#pragma unroll
    for (int u = 0; u < 5; ++u) {
      float o0 = sane(acc_o[u][0] * invl, 240.f);
      float o1 = sane(acc_o[u][1] * invl, 240.f);
      float o2 = sane(acc_o[u][2] * invl, 240.f);
      float o3 = sane(acc_o[u][3] * invl, 240.f);
      int pk = __builtin_amdgcn_cvt_pk_fp8_f32(o0, o1, 0, false);
      pk = __builtin_amdgcn_cvt_pk_fp8_f32(o2, o3, pk, true);
      *(int*)(ob + u * 16 + g * 4) = pk;
    }
  }
}

// -------------------- Kernel B: fc GEMM fp8xfp8, NO LDS, 1-wave blocks --------------------
// grid 1280 = 128 row-tiles x 10 col-tiles = exactly 5 blocks/CU. A read directly from
// attn8 rows (8B frags); B from fragment-major Wf8 (coalesced 512B chunks, L2-resident).
__global__ __launch_bounds__(64, 4) void fc_kernel(
    const unsigned char* __restrict__ attn8, const unsigned char* __restrict__ wf8,
    const float* __restrict__ fcb, const float* __restrict__ gamma,
    const float* __restrict__ qres, unsigned short* __restrict__ xout) {
  const int lane = threadIdx.x;
  const int col = lane & 15, g = lane >> 4;
  const int blk = blockIdx.x;
  const int rt = blk / 10, cn = blk - rt * 10;
  const int rbase = rt * 64, cbase = cn * 64;

  f32x4 acc[4][4];
#pragma unroll
  for (int m = 0; m < 4; ++m)
#pragma unroll
    for (int n = 0; n < 4; ++n) {
      f32x4 z = {0.f, 0.f, 0.f, 0.f};
      acc[m][n] = z;
    }

  for (int kc = 0; kc < 20; ++kc) {
    long af[4], bfr[4];
#pragma unroll
    for (int m = 0; m < 4; ++m)
      af[m] = *(const long*)(attn8 + (size_t)(rbase + m * 16 + col) * DM_ + kc * 32 + g * 8);
#pragma unroll
    for (int n = 0; n < 4; ++n)
      bfr[n] = *(const long*)(wf8 + ((size_t)(cn * 4 + n) * 20 + kc) * 512 + col * 32 + g * 8);
#pragma unroll
    for (int m = 0; m < 4; ++m)
#pragma unroll
      for (int n = 0; n < 4; ++n)
        acc[m][n] = __builtin_amdgcn_mfma_f32_16x16x32_fp8_fp8(af[m], bfr[n], acc[m][n], 0, 0, 0);
  }

  int jcol[4];
  float fb4[4], gm[4];
#pragma unroll
  for (int n = 0; n < 4; ++n) {
    jcol[n] = cbase + n * 16 + col;
    fb4[n] = fcb[jcol[n]];
    gm[n] = gamma[jcol[n]];
  }
#pragma unroll
  for (int m = 0; m < 4; ++m) {
    int rowg = rbase + m * 16 + g * 4;
#pragma unroll
    for (int j = 0; j < 4; ++j) {
      int row = rowg + j;
#pragma unroll
      for (int n = 0; n < 4; ++n) {
        float xv = (acc[m][n][j] + fb4[n]) * gm[n] + qres[(size_t)row * DM_ + jcol[n]];
        xout[(size_t)row * DM_ + jcol[n]] = f2bf(sane(xv, 1e5f));
      }
    }
  }
}

// -------------------- Kernel C: LayerNorm (x bf16 -> y fp32) --------------------
__global__ __launch_bounds__(256) void ln_kernel(
    const unsigned short* __restrict__ x, const float* __restrict__ lw,
    const float* __restrict__ lb, float* __restrict__ y) {
  const int wid = threadIdx.x >> 6, lane = threadIdx.x & 63;
  const int row = blockIdx.x * 4 + wid;
  const unsigned short* xr = x + (size_t)row * DM_;

  unsigned int u[5];
  float s = 0.f, ss = 0.f;
#pragma unroll
  for (int i = 0; i < 5; ++i) {
    u[i] = *(const unsigned int*)(xr + 2 * (lane + 64 * i));
    float a0 = bf2f((unsigned short)(u[i] & 0xffff));
    float a1 = bf2f((unsigned short)(u[i] >> 16));
    s += a0 + a1;
    ss += a0 * a0 + a1 * a1;
  }
#pragma unroll
  for (int d = 1; d < 64; d <<= 1) {
    s += __shfl_xor(s, d);
    ss += __shfl_xor(ss, d);
  }
  const float mu = s * (1.f / 640.f);
  const float var = ss * (1.f / 640.f) - mu * mu;
  const float rstd = rsqrtf(var + 1e-5f);

  float* yr = y + (size_t)row * DM_;
#pragma unroll
  for (int i = 0; i < 5; ++i) {
    int c0 = 2 * (lane + 64 * i);
    float a0 = bf2f((unsigned short)(u[i] & 0xffff));
    float a1 = bf2f((unsigned short)(u[i] >> 16));
    float2 wv = *(const float2*)(lw + c0);
    float2 bv = *(const float2*)(lb + c0);
    float2 out;
    out.x = (a0 - mu) * rstd * wv.x + bv.x;
    out.y = (a1 - mu) * rstd * wv.y + bv.y;
    *(float2*)(yr + c0) = out;
  }
}

extern "C" void kernel_launch(void* const* d_in, const int* in_sizes, int n_in,
                              void* d_out, int out_size, void* d_ws, size_t ws_size,
                              hipStream_t stream) {
  const float* q = (const float*)d_in[0];
  const float* k = (const float*)d_in[1];
  const float* v = (const float*)d_in[2];
  const float* fw = (const float*)d_in[3];
  const float* fb = (const float*)d_in[4];
  const float* g1 = (const float*)d_in[5];
  const float* lw = (const float*)d_in[6];
  const float* lb = (const float*)d_in[7];

  unsigned short* vtp = (unsigned short*)d_out;                   // 10.62 MB V' frags
  unsigned char* attn8 = (unsigned char*)d_out + ATTN8_OFF;       // 5.24 MB fp8 attn
  unsigned char* wf8 = (unsigned char*)d_out + WF8_OFF;           // 0.41 MB fp8 W frags
  unsigned short* kp = (unsigned short*)d_ws;                     // 10.49 MB K' frags
  unsigned short* xws = (unsigned short*)d_ws;                    // x overwrites Kp
  float* y = (float*)d_out;                                        // final overwrite

  wcvt_kernel<<<dim3(400), dim3(256), 0, stream>>>(fw, wf8);
  prep_kernel<<<dim3(64 * 16), dim3(256), 0, stream>>>(k, v, kp, vtp);
  attn_kernel<<<dim3(64 * 8), dim3(256), 0, stream>>>(q, kp, vtp, attn8);
  fc_kernel<<<dim3(1280), dim3(64), 0, stream>>>(attn8, wf8, fb, g1, q, xws);
  ln_kernel<<<dim3(8192 / 4), dim3(256), 0, stream>>>(xws, lw, lb, y);
}

// Round 9
// 94.076 us; speedup vs baseline: 1.7153x; 1.7153x over previous
//
#include <hip/hip_runtime.h>

#define B_ 8
#define L_ 1024
#define H_ 8
#define DM_ 640

typedef __attribute__((ext_vector_type(8))) short bf16x8;
typedef __attribute__((ext_vector_type(4))) short bf16x4;
typedef __attribute__((ext_vector_type(4))) float f32x4;
typedef __attribute__((ext_vector_type(2))) float f32x2;
typedef __attribute__((ext_vector_type(2))) int i32x2;
typedef __attribute__((ext_vector_type(4))) int i32x4;
typedef __attribute__((ext_vector_type(4))) unsigned short us4;
typedef __attribute__((ext_vector_type(8))) unsigned short us8;

#if __has_builtin(__builtin_amdgcn_exp2f)
#define EXP2F __builtin_amdgcn_exp2f
#else
#define EXP2F exp2f
#endif

#define C1F 0.22195308f  // 2*log2(e)/13
#define C2F 0.11097654f  // log2(e)/13

// d_out layout: [0, 10616832)            Vtp bf16 V' tiles [64bh][16kt][81 rows][64 keys]
//                                        rows 0..79 = w'*V transposed, row 80 = w'
//               [10616832, 15859712)     attn fp8 e4m3 [8192][640]
// ws layout:    [0, 10485760)            Kp bf16(K*C1) [64bh][1024][80]
//               (fc overwrites ws with x bf16; ln overwrites d_out with y)
#define VTP_TILE_SHORTS 5184     // 81*64
#define ATTN8_OFF 10616832       // bytes into d_out

__device__ __forceinline__ unsigned short f2bf(float f) {
  unsigned int u = __builtin_bit_cast(unsigned int, f);
  u += 0x7fffu + ((u >> 16) & 1u);
  return (unsigned short)(u >> 16);
}
__device__ __forceinline__ float bf2f(unsigned short h) {
  unsigned int u = ((unsigned int)h) << 16;
  return __builtin_bit_cast(float, u);
}
__device__ __forceinline__ float sane(float x, float lim) {
  return fminf(fmaxf(x, -lim), lim);  // also maps NaN -> -lim
}
__device__ __forceinline__ unsigned cvt_pk_bf16(float a, float b) {
  unsigned r;
  asm("v_cvt_pk_bf16_f32 %0, %1, %2" : "=v"(r) : "v"(a), "v"(b));
  return r;
}

// -------------------- Kernel 0: prep --------------------
// Kp = bf16(k*C1) row-major [ws]; Vtp tile rows 0..79 = bf16(w'*v) transposed,
// row 80 = bf16(w'), w' = exp2((80-||k||^2)*C2) (constant cancels in num/denom).
__global__ __launch_bounds__(256) void prep_kernel(
    const float* __restrict__ kg, const float* __restrict__ vg,
    unsigned short* __restrict__ Kp, unsigned short* __restrict__ Vtp) {
  __shared__ float V_lds[64 * 81];
  __shared__ float w_lds[64];
  const int tid = threadIdx.x;
  const int bh = blockIdx.x >> 4, kt = blockIdx.x & 15;
  const int b = bh >> 3, h = bh & 7;
  const int key = tid >> 2, part = tid & 3;
  const int keyg = kt * 64 + key;

  const float* krow = kg + (size_t)(b * L_ + keyg) * DM_ + h * 80 + part * 20;
  const float* vrow = vg + (size_t)(b * L_ + keyg) * DM_ + h * 80 + part * 20;
  unsigned short* kpr = Kp + ((size_t)bh * L_ + keyg) * 80 + part * 20;

  float ssq = 0.f;
#pragma unroll
  for (int i = 0; i < 5; ++i) {
    float4 f = *(const float4*)(krow + 4 * i);
    ssq += f.x * f.x + f.y * f.y + f.z * f.z + f.w * f.w;
    us4 h4 = {f2bf(f.x * C1F), f2bf(f.y * C1F), f2bf(f.z * C1F), f2bf(f.w * C1F)};
    *(us4*)(kpr + 4 * i) = h4;
    float4 g4 = *(const float4*)(vrow + 4 * i);
    int d0 = part * 20 + 4 * i;
    V_lds[key * 81 + d0 + 0] = g4.x;
    V_lds[key * 81 + d0 + 1] = g4.y;
    V_lds[key * 81 + d0 + 2] = g4.z;
    V_lds[key * 81 + d0 + 3] = g4.w;
  }
  ssq += __shfl_xor(ssq, 1);
  ssq += __shfl_xor(ssq, 2);
  if (part == 0) w_lds[key] = EXP2F((80.f - ssq) * C2F);
  __syncthreads();

  unsigned short* vt = Vtp + (size_t)(bh * 16 + kt) * VTP_TILE_SHORTS;
#pragma unroll
  for (int r = 0; r < 11; ++r) {
    int p = r * 256 + tid;
    if (p < 81 * 32) {
      int dv = p >> 5, kp = (p & 31) * 2;
      float wa = w_lds[kp], wb = w_lds[kp + 1];
      float va = (dv < 80) ? V_lds[kp * 81 + dv] * wa : wa;
      float vb = (dv < 80) ? V_lds[(kp + 1) * 81 + dv] * wb : wb;
      *(unsigned*)(vt + dv * 64 + kp) =
          (unsigned)f2bf(va) | ((unsigned)f2bf(vb) << 16);
    }
  }
}

// -------------------- Kernel A: flash attention --------------------
// 2-wave blocks, QBLK=64 (each wave: 16 q-rows x 2 subtiles at +0/+32). Grid 1024
// -> ~4 independent blocks/CU: small decorrelated barrier domains cover each
// other's staging drains. Single-buffered LDS (K 13.3KB + V 12.2KB + w' 128B);
// loads for kt+1 issued before compute(kt). Swapped QK^T; p = exp2(C1*q.k)
// (bounded, no max tracking); PV via 16x16x16 MFMA consumes P in-register;
// l = sum_k w'_k p_k in VALU (+2 shfl at end); output fp8.
#define KSTR 104  // shorts
#define VSTR 76   // shorts (odd-pair spread -> conflict-free b64 PV reads)

__global__ __launch_bounds__(128) void attn_kernel(
    const float* __restrict__ qg, const unsigned short* __restrict__ Kp,
    const unsigned short* __restrict__ Vtp, unsigned char* __restrict__ attn8) {
  __shared__ __align__(16) unsigned short K_lds[64 * KSTR];
  __shared__ __align__(16) unsigned short Vt_lds[80 * VSTR];
  __shared__ __align__(16) unsigned short w_sh[64];

  const int tid = threadIdx.x;
  const int wid = tid >> 6, lane = tid & 63;
  const int col = lane & 15, g = lane >> 4;
  const int bx = blockIdx.x;
  const int bh = bx & 63, qt = bx >> 6;  // same-bh blocks 64 apart -> same XCD slot
  const int b = bh >> 3, h = bh & 7;

  // zero K pad dims [80,96) once (staging writes only [0,80))
  if (tid < 64) {
    us8 z = {0, 0, 0, 0, 0, 0, 0, 0};
    *(us8*)&K_lds[tid * KSTR + 80] = z;
    *(us8*)&K_lds[tid * KSTR + 88] = z;
  }

  // staging coords: K/V = 640 us8 chunks each (5 per thread), w = 8 chunks
  int krr[5], kcc[5], vrr[5], vcc[5];
#pragma unroll
  for (int i = 0; i < 5; ++i) {
    int f = tid + 128 * i;
    krr[i] = f / 10;
    kcc[i] = f - krr[i] * 10;
    vrr[i] = f >> 3;
    vcc[i] = f & 7;
  }
  const unsigned short* kslice = Kp + (size_t)bh * L_ * 80;
  const unsigned short* vslice = Vtp + (size_t)(bh * 16) * VTP_TILE_SHORTS;

  us8 sk[5], sv[5], sw;
  auto load_tile = [&](int kt) {
    const unsigned short* kb = kslice + (size_t)kt * 5120;
    const unsigned short* vb = vslice + (size_t)kt * VTP_TILE_SHORTS;
#pragma unroll
    for (int i = 0; i < 5; ++i) {
      sk[i] = *(const us8*)(kb + krr[i] * 80 + kcc[i] * 8);
      sv[i] = *(const us8*)(vb + vrr[i] * 64 + vcc[i] * 8);
    }
    if (tid < 8) sw = *(const us8*)(vb + 5120 + tid * 8);
  };
  auto write_tile = [&]() {
#pragma unroll
    for (int i = 0; i < 5; ++i) {
      *(us8*)&K_lds[krr[i] * KSTR + kcc[i] * 8] = sk[i];
      *(us8*)&Vt_lds[vrr[i] * VSTR + vcc[i] * 8] = sv[i];
    }
    if (tid < 8) *(us8*)&w_sh[tid * 8] = sw;
  };

  // Q fragments (B-operand: lane col = q-row, dims g*8+e), subtiles +0/+32
  bf16x8 qa0[3], qa1[3];
  {
    const int qr0 = qt * 64 + wid * 16 + col;
#pragma unroll
    for (int s = 0; s < 2; ++s) {
      const float* qr = qg + (size_t)(b * L_ + qr0 + s * 32) * DM_ + h * 80;
      bf16x8* qa = s ? qa1 : qa0;
#pragma unroll
      for (int c = 0; c < 3; ++c) {
        int d0 = c * 32 + g * 8;
        if (d0 < 80) {
          float4 f0 = *(const float4*)(qr + d0);
          float4 f1 = *(const float4*)(qr + d0 + 4);
          qa[c][0] = (short)f2bf(f0.x); qa[c][1] = (short)f2bf(f0.y);
          qa[c][2] = (short)f2bf(f0.z); qa[c][3] = (short)f2bf(f0.w);
          qa[c][4] = (short)f2bf(f1.x); qa[c][5] = (short)f2bf(f1.y);
          qa[c][6] = (short)f2bf(f1.z); qa[c][7] = (short)f2bf(f1.w);
        } else {
#pragma unroll
          for (int e = 0; e < 8; ++e) qa[c][e] = 0;
        }
      }
    }
  }

  f32x4 acc_o0[5], acc_o1[5];
#pragma unroll
  for (int u = 0; u < 5; ++u) {
    f32x4 z = {0.f, 0.f, 0.f, 0.f};
    acc_o0[u] = z;
    acc_o1[u] = z;
  }
  float lp0 = 0.f, lp1 = 0.f;

  load_tile(0);

  for (int kt = 0; kt < 16; ++kt) {
    __syncthreads();  // all waves done reading previous tile
    write_tile();
    __syncthreads();  // tile kt visible
    if (kt < 15) load_tile(kt + 1);  // next tile's loads hide under compute

    // QK^T: accS[t][r] = C1*q.k for key = t*16+g*4+r, q = col
    f32x4 accS0[4], accS1[4];
#pragma unroll
    for (int t = 0; t < 4; ++t) {
      f32x4 z = {0.f, 0.f, 0.f, 0.f};
      accS0[t] = z;
      accS1[t] = z;
    }
#pragma unroll
    for (int t = 0; t < 4; ++t)
#pragma unroll
      for (int c = 0; c < 3; ++c) {
        bf16x8 kf = *(const bf16x8*)&K_lds[(t * 16 + col) * KSTR + c * 32 + g * 8];
        accS0[t] = __builtin_amdgcn_mfma_f32_16x16x32_bf16(kf, qa0[c], accS0[t], 0, 0, 0);
        accS1[t] = __builtin_amdgcn_mfma_f32_16x16x32_bf16(kf, qa1[c], accS1[t], 0, 0, 0);
      }

    // softmax numerators, l-dot (w' broadcast from LDS), pack, PV
#pragma unroll
    for (int t = 0; t < 4; ++t) {
      us4 w4 = *(const us4*)&w_sh[t * 16 + g * 4];
      float w0 = bf2f(w4[0]), w1 = bf2f(w4[1]), w2 = bf2f(w4[2]), w3 = bf2f(w4[3]);
      float p00 = EXP2F(accS0[t][0]), p01 = EXP2F(accS0[t][1]);
      float p02 = EXP2F(accS0[t][2]), p03 = EXP2F(accS0[t][3]);
      float p10 = EXP2F(accS1[t][0]), p11 = EXP2F(accS1[t][1]);
      float p12 = EXP2F(accS1[t][2]), p13 = EXP2F(accS1[t][3]);
      lp0 += p00 * w0 + p01 * w1 + p02 * w2 + p03 * w3;
      lp1 += p10 * w0 + p11 * w1 + p12 * w2 + p13 * w3;
      i32x2 pw0 = {(int)cvt_pk_bf16(p00, p01), (int)cvt_pk_bf16(p02, p03)};
      i32x2 pw1 = {(int)cvt_pk_bf16(p10, p11), (int)cvt_pk_bf16(p12, p13)};
      bf16x4 pf0 = __builtin_bit_cast(bf16x4, pw0);
      bf16x4 pf1 = __builtin_bit_cast(bf16x4, pw1);
#pragma unroll
      for (int u = 0; u < 5; ++u) {
        bf16x4 vf = *(const bf16x4*)&Vt_lds[(u * 16 + col) * VSTR + t * 16 + g * 4];
        acc_o0[u] = __builtin_amdgcn_mfma_f32_16x16x16bf16_1k(vf, pf0, acc_o0[u], 0, 0, 0);
        acc_o1[u] = __builtin_amdgcn_mfma_f32_16x16x16bf16_1k(vf, pf1, acc_o1[u], 0, 0, 0);
      }
    }
  }

  // l = cross-g reduce of lp (terms positive -> l > 0); fp8 output
  float l0 = lp0 + __shfl_xor(lp0, 16);
  l0 += __shfl_xor(l0, 32);
  float l1 = lp1 + __shfl_xor(lp1, 16);
  l1 += __shfl_xor(l1, 32);
#pragma unroll
  for (int s = 0; s < 2; ++s) {
    f32x4* acc_o = s ? acc_o1 : acc_o0;
    float invl = 1.0f / fmaxf(s ? l1 : l0, 1e-30f);
    const int qrow = qt * 64 + s * 32 + wid * 16 + col;
    unsigned char* ob = attn8 + (size_t)(b * L_ + qrow) * DM_ + h * 80;
#pragma unroll
    for (int u = 0; u < 5; ++u) {
      float o0 = sane(acc_o[u][0] * invl, 240.f);
      float o1 = sane(acc_o[u][1] * invl, 240.f);
      float o2 = sane(acc_o[u][2] * invl, 240.f);
      float o3 = sane(acc_o[u][3] * invl, 240.f);
      int pk = __builtin_amdgcn_cvt_pk_fp8_f32(o0, o1, 0, false);
      pk = __builtin_amdgcn_cvt_pk_fp8_f32(o2, o3, pk, true);
      *(int*)(ob + u * 16 + g * 4) = pk;
    }
  }
}

// -------------------- Kernel B: fc GEMM (bf16; A from fp8), T14 dbuf, 1 barrier/k ------
#define BSTR 40  // shorts
__global__ __launch_bounds__(256) void fc_kernel(
    const unsigned char* __restrict__ attn8, const float* __restrict__ w,
    const float* __restrict__ fcb, const float* __restrict__ gamma,
    const float* __restrict__ qres, unsigned short* __restrict__ xout) {
  __shared__ __align__(16) unsigned short A_lds[2][128 * BSTR];
  __shared__ __align__(16) unsigned short B_lds[2][128 * BSTR];

  const int tid = threadIdx.x;
  const int wid = tid >> 6, lane = tid & 63;
  const int col = lane & 15, g = lane >> 4;
  const int rt = blockIdx.x / 5, ct = blockIdx.x % 5;
  const int wm = wid >> 1, wn = wid & 1;
  const int r = tid >> 1, seg = tid & 1;

  f32x4 acc[4][4];
#pragma unroll
  for (int m = 0; m < 4; ++m)
#pragma unroll
    for (int n = 0; n < 4; ++n) {
      f32x4 z = {0.f, 0.f, 0.f, 0.f};
      acc[m][n] = z;
    }

  uint4 sa;
  float4 sb[4];
  auto load_k = [&](int kc) {
    sa = *(const uint4*)(attn8 + (size_t)(rt * 128 + r) * DM_ + kc * 32 + seg * 16);
    const float* wsrc = w + (size_t)(ct * 128 + r) * DM_ + kc * 32 + seg * 16;
#pragma unroll
    for (int i = 0; i < 4; ++i) sb[i] = *(const float4*)(wsrc + 4 * i);
  };
  auto write_k = [&](int bf) {
    const unsigned* adw = (const unsigned*)&sa;
#pragma unroll
    for (int wde = 0; wde < 4; ++wde) {
      f32x2 lo = __builtin_amdgcn_cvt_pk_f32_fp8(adw[wde], false);
      f32x2 hi = __builtin_amdgcn_cvt_pk_f32_fp8(adw[wde], true);
      us4 h4 = {f2bf(lo[0]), f2bf(lo[1]), f2bf(hi[0]), f2bf(hi[1])};
      *(us4*)&A_lds[bf][r * BSTR + seg * 16 + wde * 4] = h4;
    }
#pragma unroll
    for (int i = 0; i < 4; ++i) {
      us4 h4 = {f2bf(sb[i].x), f2bf(sb[i].y), f2bf(sb[i].z), f2bf(sb[i].w)};
      *(us4*)&B_lds[bf][r * BSTR + seg * 16 + 4 * i] = h4;
    }
  };

  load_k(0);
  write_k(0);
  __syncthreads();

  for (int kc = 0; kc < 20; ++kc) {
    const int cur = kc & 1;
    if (kc < 19) load_k(kc + 1);

    bf16x8 af[4], bfr[4];
#pragma unroll
    for (int m = 0; m < 4; ++m)
      af[m] = *(const bf16x8*)&A_lds[cur][(wm * 64 + m * 16 + col) * BSTR + g * 8];
#pragma unroll
    for (int n = 0; n < 4; ++n)
      bfr[n] = *(const bf16x8*)&B_lds[cur][(wn * 64 + n * 16 + col) * BSTR + g * 8];
#pragma unroll
    for (int m = 0; m < 4; ++m)
#pragma unroll
      for (int n = 0; n < 4; ++n)
        acc[m][n] = __builtin_amdgcn_mfma_f32_16x16x32_bf16(af[m], bfr[n], acc[m][n], 0, 0, 0);

    if (kc < 19) {
      write_k(cur ^ 1);
      __syncthreads();
    }
  }

  int jcol[4];
  float fb4[4], gm[4];
#pragma unroll
  for (int n = 0; n < 4; ++n) {
    jcol[n] = ct * 128 + wn * 64 + n * 16 + col;
    fb4[n] = fcb[jcol[n]];
    gm[n] = gamma[jcol[n]];
  }
#pragma unroll
  for (int m = 0; m < 4; ++m) {
    int rowg = rt * 128 + wm * 64 + m * 16 + g * 4;
#pragma unroll
    for (int j = 0; j < 4; ++j) {
      int row = rowg + j;
#pragma unroll
      for (int n = 0; n < 4; ++n) {
        float xv = (acc[m][n][j] + fb4[n]) * gm[n] + qres[(size_t)row * DM_ + jcol[n]];
        xout[(size_t)row * DM_ + jcol[n]] = f2bf(sane(xv, 1e5f));
      }
    }
  }
}

// -------------------- Kernel C: LayerNorm (x bf16 -> y fp32) --------------------
__global__ __launch_bounds__(256) void ln_kernel(
    const unsigned short* __restrict__ x, const float* __restrict__ lw,
    const float* __restrict__ lb, float* __restrict__ y) {
  const int wid = threadIdx.x >> 6, lane = threadIdx.x & 63;
  const int row = blockIdx.x * 4 + wid;
  const unsigned short* xr = x + (size_t)row * DM_;

  unsigned int u[5];
  float s = 0.f, ss = 0.f;
#pragma unroll
  for (int i = 0; i < 5; ++i) {
    u[i] = *(const unsigned int*)(xr + 2 * (lane + 64 * i));
    float a0 = bf2f((unsigned short)(u[i] & 0xffff));
    float a1 = bf2f((unsigned short)(u[i] >> 16));
    s += a0 + a1;
    ss += a0 * a0 + a1 * a1;
  }
#pragma unroll
  for (int d = 1; d < 64; d <<= 1) {
    s += __shfl_xor(s, d);
    ss += __shfl_xor(ss, d);
  }
  const float mu = s * (1.f / 640.f);
  const float var = ss * (1.f / 640.f) - mu * mu;
  const float rstd = rsqrtf(var + 1e-5f);

  float* yr = y + (size_t)row * DM_;
#pragma unroll
  for (int i = 0; i < 5; ++i) {
    int c0 = 2 * (lane + 64 * i);
    float a0 = bf2f((unsigned short)(u[i] & 0xffff));
    float a1 = bf2f((unsigned short)(u[i] >> 16));
    float2 wv = *(const float2*)(lw + c0);
    float2 bv = *(const float2*)(lb + c0);
    float2 out;
    out.x = (a0 - mu) * rstd * wv.x + bv.x;
    out.y = (a1 - mu) * rstd * wv.y + bv.y;
    *(float2*)(yr + c0) = out;
  }
}

extern "C" void kernel_launch(void* const* d_in, const int* in_sizes, int n_in,
                              void* d_out, int out_size, void* d_ws, size_t ws_size,
                              hipStream_t stream) {
  const float* q = (const float*)d_in[0];
  const float* k = (const float*)d_in[1];
  const float* v = (const float*)d_in[2];
  const float* fw = (const float*)d_in[3];
  const float* fb = (const float*)d_in[4];
  const float* g1 = (const float*)d_in[5];
  const float* lw = (const float*)d_in[6];
  const float* lb = (const float*)d_in[7];

  unsigned short* vtp = (unsigned short*)d_out;                   // 10.62 MB V' tiles
  unsigned char* attn8 = (unsigned char*)d_out + ATTN8_OFF;       // 5.24 MB fp8 attn
  unsigned short* kp = (unsigned short*)d_ws;                     // 10.49 MB Kp
  unsigned short* xws = (unsigned short*)d_ws;                    // x overwrites Kp
  float* y = (float*)d_out;                                        // final overwrite

  prep_kernel<<<dim3(64 * 16), dim3(256), 0, stream>>>(k, v, kp, vtp);
  attn_kernel<<<dim3(64 * 16), dim3(128), 0, stream>>>(q, kp, vtp, attn8);
  fc_kernel<<<dim3((8192 / 128) * 5), dim3(256), 0, stream>>>(attn8, fw, fb, g1, q, xws);
  ln_kernel<<<dim3(8192 / 4), dim3(256), 0, stream>>>(xws, lw, lb, y);
}

// Round 10
// 84.014 us; speedup vs baseline: 1.9207x; 1.1198x over previous
//
#include <hip/hip_runtime.h>

#define B_ 8
#define L_ 1024
#define H_ 8
#define DM_ 640

typedef __attribute__((ext_vector_type(8))) short bf16x8;
typedef __attribute__((ext_vector_type(4))) short bf16x4;
typedef __attribute__((ext_vector_type(4))) float f32x4;
typedef __attribute__((ext_vector_type(2))) float f32x2;
typedef __attribute__((ext_vector_type(2))) int i32x2;
typedef __attribute__((ext_vector_type(4))) unsigned short us4;
typedef __attribute__((ext_vector_type(8))) unsigned short us8;

#if __has_builtin(__builtin_amdgcn_exp2f)
#define EXP2F __builtin_amdgcn_exp2f
#else
#define EXP2F exp2f
#endif

#define C1F 0.22195308f  // 2*log2(e)/13
#define C2F 0.11097654f  // log2(e)/13

// d_out layout: [0, 10616832)            Vtp bf16 V' tiles [64bh][16kt][81 rows][64 keys]
//                                        rows 0..79 = w'*V transposed, row 80 = w'
//               [10616832, 15859712)     attn fp8 e4m3 [8192][640]
// ws layout:    [0, 10485760)            Kp bf16(K*C1) [64bh][1024][80]
//               (fc overwrites ws with x bf16; ln overwrites d_out with y)
#define VTP_TILE_SHORTS 5184     // 81*64
#define ATTN8_OFF 10616832       // bytes into d_out

__device__ __forceinline__ unsigned short f2bf(float f) {
  unsigned int u = __builtin_bit_cast(unsigned int, f);
  u += 0x7fffu + ((u >> 16) & 1u);
  return (unsigned short)(u >> 16);
}
__device__ __forceinline__ float bf2f(unsigned short h) {
  unsigned int u = ((unsigned int)h) << 16;
  return __builtin_bit_cast(float, u);
}
__device__ __forceinline__ float sane(float x, float lim) {
  return fminf(fmaxf(x, -lim), lim);  // also maps NaN -> -lim
}
__device__ __forceinline__ unsigned cvt_pk_bf16(float a, float b) {
  unsigned r;
  asm("v_cvt_pk_bf16_f32 %0, %1, %2" : "=v"(r) : "v"(a), "v"(b));
  return r;
}

// -------------------- Kernel 0: prep --------------------
// Kp = bf16(k*C1) row-major [ws]; Vtp tile rows 0..79 = bf16(w'*v) transposed,
// row 80 = bf16(w'), w' = exp2((80-||k||^2)*C2) (constant cancels in num/denom).
__global__ __launch_bounds__(256) void prep_kernel(
    const float* __restrict__ kg, const float* __restrict__ vg,
    unsigned short* __restrict__ Kp, unsigned short* __restrict__ Vtp) {
  __shared__ float V_lds[64 * 81];
  __shared__ float w_lds[64];
  const int tid = threadIdx.x;
  const int bh = blockIdx.x >> 4, kt = blockIdx.x & 15;
  const int b = bh >> 3, h = bh & 7;
  const int key = tid >> 2, part = tid & 3;
  const int keyg = kt * 64 + key;

  const float* krow = kg + (size_t)(b * L_ + keyg) * DM_ + h * 80 + part * 20;
  const float* vrow = vg + (size_t)(b * L_ + keyg) * DM_ + h * 80 + part * 20;
  unsigned short* kpr = Kp + ((size_t)bh * L_ + keyg) * 80 + part * 20;

  float ssq = 0.f;
#pragma unroll
  for (int i = 0; i < 5; ++i) {
    float4 f = *(const float4*)(krow + 4 * i);
    ssq += f.x * f.x + f.y * f.y + f.z * f.z + f.w * f.w;
    us4 h4 = {f2bf(f.x * C1F), f2bf(f.y * C1F), f2bf(f.z * C1F), f2bf(f.w * C1F)};
    *(us4*)(kpr + 4 * i) = h4;
    float4 g4 = *(const float4*)(vrow + 4 * i);
    int d0 = part * 20 + 4 * i;
    V_lds[key * 81 + d0 + 0] = g4.x;
    V_lds[key * 81 + d0 + 1] = g4.y;
    V_lds[key * 81 + d0 + 2] = g4.z;
    V_lds[key * 81 + d0 + 3] = g4.w;
  }
  ssq += __shfl_xor(ssq, 1);
  ssq += __shfl_xor(ssq, 2);
  if (part == 0) w_lds[key] = EXP2F((80.f - ssq) * C2F);
  __syncthreads();

  unsigned short* vt = Vtp + (size_t)(bh * 16 + kt) * VTP_TILE_SHORTS;
#pragma unroll
  for (int r = 0; r < 11; ++r) {
    int p = r * 256 + tid;
    if (p < 81 * 32) {
      int dv = p >> 5, kp = (p & 31) * 2;
      float wa = w_lds[kp], wb = w_lds[kp + 1];
      float va = (dv < 80) ? V_lds[kp * 81 + dv] * wa : wa;
      float vb = (dv < 80) ? V_lds[(kp + 1) * 81 + dv] * wb : wb;
      *(unsigned*)(vt + dv * 64 + kp) =
          (unsigned)f2bf(va) | ((unsigned)f2bf(vb) << 16);
    }
  }
}

// -------------------- Kernel A: flash attention (r7 frame + l-in-VALU + setprio) ------
// 4-wave blocks, QBLK=128 (wave: 16 q-rows x 2 subtiles at +0/+64), grid 512,
// double-buffered LDS, ONE barrier per kt; loads for kt+1 issued before compute.
// Swapped QK^T: lane(col=q,g) holds S[key=t*16+g*4+r][q] = C1*q.k; p = exp2(S)
// (bounded, no max tracking); PV via 16x16x16 MFMA consumes P in-register;
// l = sum_k w'_k p_k in VALU (w' from 128B LDS row); output fp8.
#define KSTR 104  // shorts
#define VSTR 76   // shorts (odd-pair spread -> conflict-free b64 PV reads)

__global__ __launch_bounds__(256, 2) void attn_kernel(
    const float* __restrict__ qg, const unsigned short* __restrict__ Kp,
    const unsigned short* __restrict__ Vtp, unsigned char* __restrict__ attn8) {
  __shared__ __align__(16) unsigned short K_lds[2][64 * KSTR];
  __shared__ __align__(16) unsigned short Vt_lds[2][80 * VSTR];
  __shared__ __align__(16) unsigned short w_sh[2][64];

  const int tid = threadIdx.x;
  const int wid = tid >> 6, lane = tid & 63;
  const int col = lane & 15, g = lane >> 4;
  const int bx = blockIdx.x;
  const int bh = bx & 63, qt = bx >> 6;  // same-bh blocks 64 apart -> same XCD slot
  const int b = bh >> 3, h = bh & 7;

  // zero K pad dims [80,96) in BOTH buffers once
  if (tid < 128) {
    us8 z = {0, 0, 0, 0, 0, 0, 0, 0};
    int bufz = tid >> 6, r = tid & 63;
    *(us8*)&K_lds[bufz][r * KSTR + 80] = z;
    *(us8*)&K_lds[bufz][r * KSTR + 88] = z;
  }

  // staging coords: K = 640 us8 chunks, V = 640 (80 rows), w' = 8; 256 thr, 3 rounds
  const int ka0 = tid, ka1 = tid + 256, ka2 = tid + 512;  // ka2 if tid < 128
  const int kr0 = ka0 / 10, kc0 = ka0 - kr0 * 10;
  const int kr1 = ka1 / 10, kc1 = ka1 - kr1 * 10;
  const int kr2 = ka2 / 10, kc2 = ka2 - kr2 * 10;
  const int vr0 = ka0 >> 3, vc0 = ka0 & 7;
  const int vr1 = ka1 >> 3, vc1 = ka1 & 7;
  const int vr2 = ka2 >> 3, vc2 = ka2 & 7;

  const unsigned short* kslice = Kp + (size_t)bh * L_ * 80;
  const unsigned short* vslice = Vtp + (size_t)(bh * 16) * VTP_TILE_SHORTS;

  us8 sk0, sk1, sk2, sv0, sv1, sv2, sw;
  auto load_tile = [&](int kt) {
    const unsigned short* kb = kslice + (size_t)kt * 5120;
    const unsigned short* vb = vslice + (size_t)kt * VTP_TILE_SHORTS;
    sk0 = *(const us8*)(kb + kr0 * 80 + kc0 * 8);
    sk1 = *(const us8*)(kb + kr1 * 80 + kc1 * 8);
    if (tid < 128) sk2 = *(const us8*)(kb + kr2 * 80 + kc2 * 8);
    sv0 = *(const us8*)(vb + vr0 * 64 + vc0 * 8);
    sv1 = *(const us8*)(vb + vr1 * 64 + vc1 * 8);
    if (tid < 128) sv2 = *(const us8*)(vb + vr2 * 64 + vc2 * 8);
    if (tid < 8) sw = *(const us8*)(vb + 5120 + tid * 8);
  };
  auto write_tile = [&](int bf) {
    *(us8*)&K_lds[bf][kr0 * KSTR + kc0 * 8] = sk0;
    *(us8*)&K_lds[bf][kr1 * KSTR + kc1 * 8] = sk1;
    if (tid < 128) *(us8*)&K_lds[bf][kr2 * KSTR + kc2 * 8] = sk2;
    *(us8*)&Vt_lds[bf][vr0 * VSTR + vc0 * 8] = sv0;
    *(us8*)&Vt_lds[bf][vr1 * VSTR + vc1 * 8] = sv1;
    if (tid < 128) *(us8*)&Vt_lds[bf][vr2 * VSTR + vc2 * 8] = sv2;
    if (tid < 8) *(us8*)&w_sh[bf][tid * 8] = sw;
  };

  // Q fragments for the two subtiles (B-operand: lane col = q-row, dims g*8+e)
  bf16x8 qa0[3], qa1[3];
  {
    const int qr0 = qt * 128 + wid * 16 + col;
#pragma unroll
    for (int s = 0; s < 2; ++s) {
      const float* qr = qg + (size_t)(b * L_ + qr0 + s * 64) * DM_ + h * 80;
      bf16x8* qa = s ? qa1 : qa0;
#pragma unroll
      for (int c = 0; c < 3; ++c) {
        int d0 = c * 32 + g * 8;
        if (d0 < 80) {
          float4 f0 = *(const float4*)(qr + d0);
          float4 f1 = *(const float4*)(qr + d0 + 4);
          qa[c][0] = (short)f2bf(f0.x); qa[c][1] = (short)f2bf(f0.y);
          qa[c][2] = (short)f2bf(f0.z); qa[c][3] = (short)f2bf(f0.w);
          qa[c][4] = (short)f2bf(f1.x); qa[c][5] = (short)f2bf(f1.y);
          qa[c][6] = (short)f2bf(f1.z); qa[c][7] = (short)f2bf(f1.w);
        } else {
#pragma unroll
          for (int e = 0; e < 8; ++e) qa[c][e] = 0;
        }
      }
    }
  }

  f32x4 acc_o0[5], acc_o1[5];
#pragma unroll
  for (int u = 0; u < 5; ++u) {
    f32x4 z = {0.f, 0.f, 0.f, 0.f};
    acc_o0[u] = z;
    acc_o1[u] = z;
  }
  float lp0 = 0.f, lp1 = 0.f;

  load_tile(0);
  write_tile(0);
  __syncthreads();

  for (int kt = 0; kt < 16; ++kt) {
    const int cur = kt & 1;
    if (kt < 15) load_tile(kt + 1);  // loads in flight during compute

    // QK^T: accS[t][r] = C1*q.k for key = t*16+g*4+r, q = col
    f32x4 accS0[4], accS1[4];
#pragma unroll
    for (int t = 0; t < 4; ++t) {
      f32x4 z = {0.f, 0.f, 0.f, 0.f};
      accS0[t] = z;
      accS1[t] = z;
    }
    __builtin_amdgcn_s_setprio(1);
#pragma unroll
    for (int t = 0; t < 4; ++t)
#pragma unroll
      for (int c = 0; c < 3; ++c) {
        bf16x8 kf = *(const bf16x8*)&K_lds[cur][(t * 16 + col) * KSTR + c * 32 + g * 8];
        accS0[t] = __builtin_amdgcn_mfma_f32_16x16x32_bf16(kf, qa0[c], accS0[t], 0, 0, 0);
        accS1[t] = __builtin_amdgcn_mfma_f32_16x16x32_bf16(kf, qa1[c], accS1[t], 0, 0, 0);
      }
    __builtin_amdgcn_s_setprio(0);

    // softmax numerators, l-dot (w' from LDS), pack, PV
#pragma unroll
    for (int t = 0; t < 4; ++t) {
      us4 w4 = *(const us4*)&w_sh[cur][t * 16 + g * 4];
      float w0 = bf2f(w4[0]), w1 = bf2f(w4[1]), w2 = bf2f(w4[2]), w3 = bf2f(w4[3]);
      float p00 = EXP2F(accS0[t][0]), p01 = EXP2F(accS0[t][1]);
      float p02 = EXP2F(accS0[t][2]), p03 = EXP2F(accS0[t][3]);
      float p10 = EXP2F(accS1[t][0]), p11 = EXP2F(accS1[t][1]);
      float p12 = EXP2F(accS1[t][2]), p13 = EXP2F(accS1[t][3]);
      lp0 += p00 * w0 + p01 * w1 + p02 * w2 + p03 * w3;
      lp1 += p10 * w0 + p11 * w1 + p12 * w2 + p13 * w3;
      i32x2 pw0 = {(int)cvt_pk_bf16(p00, p01), (int)cvt_pk_bf16(p02, p03)};
      i32x2 pw1 = {(int)cvt_pk_bf16(p10, p11), (int)cvt_pk_bf16(p12, p13)};
      bf16x4 pf0 = __builtin_bit_cast(bf16x4, pw0);
      bf16x4 pf1 = __builtin_bit_cast(bf16x4, pw1);
      __builtin_amdgcn_s_setprio(1);
#pragma unroll
      for (int u = 0; u < 5; ++u) {
        bf16x4 vf = *(const bf16x4*)&Vt_lds[cur][(u * 16 + col) * VSTR + t * 16 + g * 4];
        acc_o0[u] = __builtin_amdgcn_mfma_f32_16x16x16bf16_1k(vf, pf0, acc_o0[u], 0, 0, 0);
        acc_o1[u] = __builtin_amdgcn_mfma_f32_16x16x16bf16_1k(vf, pf1, acc_o1[u], 0, 0, 0);
      }
      __builtin_amdgcn_s_setprio(0);
    }

    if (kt < 15) {
      write_tile(cur ^ 1);  // buf cur^1's readers finished before the last barrier
      __syncthreads();
    }
  }

  // l = cross-g reduce of lp (terms positive -> l > 0); fp8 output
  float l0 = lp0 + __shfl_xor(lp0, 16);
  l0 += __shfl_xor(l0, 32);
  float l1 = lp1 + __shfl_xor(lp1, 16);
  l1 += __shfl_xor(l1, 32);
#pragma unroll
  for (int s = 0; s < 2; ++s) {
    f32x4* acc_o = s ? acc_o1 : acc_o0;
    float invl = 1.0f / fmaxf(s ? l1 : l0, 1e-30f);
    const int qrow = qt * 128 + s * 64 + wid * 16 + col;
    unsigned char* ob = attn8 + (size_t)(b * L_ + qrow) * DM_ + h * 80;
#pragma unroll
    for (int u = 0; u < 5; ++u) {
      float o0 = sane(acc_o[u][0] * invl, 240.f);
      float o1 = sane(acc_o[u][1] * invl, 240.f);
      float o2 = sane(acc_o[u][2] * invl, 240.f);
      float o3 = sane(acc_o[u][3] * invl, 240.f);
      int pk = __builtin_amdgcn_cvt_pk_fp8_f32(o0, o1, 0, false);
      pk = __builtin_amdgcn_cvt_pk_fp8_f32(o2, o3, pk, true);
      *(int*)(ob + u * 16 + g * 4) = pk;
    }
  }
}

// -------------------- Kernel B: fc GEMM, 64x64 tiles, grid 1280 (~5 blocks/CU) --------
// bf16 MFMA; A upconverted from fp8 in staging; dbuf, 1 barrier/k-chunk.
#define BSTR 40  // shorts
__global__ __launch_bounds__(256) void fc_kernel(
    const unsigned char* __restrict__ attn8, const float* __restrict__ w,
    const float* __restrict__ fcb, const float* __restrict__ gamma,
    const float* __restrict__ qres, unsigned short* __restrict__ xout) {
  __shared__ __align__(16) unsigned short A_lds[2][64 * BSTR];
  __shared__ __align__(16) unsigned short B_lds[2][64 * BSTR];

  const int tid = threadIdx.x;
  const int wid = tid >> 6, lane = tid & 63;
  const int col = lane & 15, g = lane >> 4;
  const int rt = blockIdx.x / 10, cn = blockIdx.x % 10;
  const int wm = wid >> 1, wn = wid & 1;
  const int r = tid >> 2, sg = tid & 3;  // 4 threads per 64-elem row segment

  f32x4 acc[2][2];
#pragma unroll
  for (int m = 0; m < 2; ++m)
#pragma unroll
    for (int n = 0; n < 2; ++n) {
      f32x4 z = {0.f, 0.f, 0.f, 0.f};
      acc[m][n] = z;
    }

  uint2 sa;
  float4 sb0, sb1;
  auto load_k = [&](int kc) {
    sa = *(const uint2*)(attn8 + (size_t)(rt * 64 + r) * DM_ + kc * 32 + sg * 8);
    const float* wsrc = w + (size_t)(cn * 64 + r) * DM_ + kc * 32 + sg * 8;
    sb0 = *(const float4*)wsrc;
    sb1 = *(const float4*)(wsrc + 4);
  };
  auto write_k = [&](int bf) {
    const unsigned* adw = (const unsigned*)&sa;
    unsigned ow[4];
#pragma unroll
    for (int d = 0; d < 2; ++d) {
      f32x2 lo = __builtin_amdgcn_cvt_pk_f32_fp8(adw[d], false);
      f32x2 hi = __builtin_amdgcn_cvt_pk_f32_fp8(adw[d], true);
      ow[2 * d] = cvt_pk_bf16(lo[0], lo[1]);
      ow[2 * d + 1] = cvt_pk_bf16(hi[0], hi[1]);
    }
    *(uint4*)&A_lds[bf][r * BSTR + sg * 8] =
        *(const uint4*)ow;
    unsigned bw[4] = {cvt_pk_bf16(sb0.x, sb0.y), cvt_pk_bf16(sb0.z, sb0.w),
                      cvt_pk_bf16(sb1.x, sb1.y), cvt_pk_bf16(sb1.z, sb1.w)};
    *(uint4*)&B_lds[bf][r * BSTR + sg * 8] = *(const uint4*)bw;
  };

  load_k(0);
  write_k(0);
  __syncthreads();

  for (int kc = 0; kc < 20; ++kc) {
    const int cur = kc & 1;
    if (kc < 19) load_k(kc + 1);

    bf16x8 af[2], bfr[2];
#pragma unroll
    for (int m = 0; m < 2; ++m)
      af[m] = *(const bf16x8*)&A_lds[cur][(wm * 32 + m * 16 + col) * BSTR + g * 8];
#pragma unroll
    for (int n = 0; n < 2; ++n)
      bfr[n] = *(const bf16x8*)&B_lds[cur][(wn * 32 + n * 16 + col) * BSTR + g * 8];
#pragma unroll
    for (int m = 0; m < 2; ++m)
#pragma unroll
      for (int n = 0; n < 2; ++n)
        acc[m][n] = __builtin_amdgcn_mfma_f32_16x16x32_bf16(af[m], bfr[n], acc[m][n], 0, 0, 0);

    if (kc < 19) {
      write_k(cur ^ 1);
      __syncthreads();
    }
  }

  int jcol[2];
  float fb2[2], gm[2];
#pragma unroll
  for (int n = 0; n < 2; ++n) {
    jcol[n] = cn * 64 + wn * 32 + n * 16 + col;
    fb2[n] = fcb[jcol[n]];
    gm[n] = gamma[jcol[n]];
  }
#pragma unroll
  for (int m = 0; m < 2; ++m) {
    int rowg = rt * 64 + wm * 32 + m * 16 + g * 4;
#pragma unroll
    for (int j = 0; j < 4; ++j) {
      int row = rowg + j;
#pragma unroll
      for (int n = 0; n < 2; ++n) {
        float xv = (acc[m][n][j] + fb2[n]) * gm[n] + qres[(size_t)row * DM_ + jcol[n]];
        xout[(size_t)row * DM_ + jcol[n]] = f2bf(sane(xv, 1e5f));
      }
    }
  }
}

// -------------------- Kernel C: LayerNorm (x bf16 -> y fp32) --------------------
__global__ __launch_bounds__(256) void ln_kernel(
    const unsigned short* __restrict__ x, const float* __restrict__ lw,
    const float* __restrict__ lb, float* __restrict__ y) {
  const int wid = threadIdx.x >> 6, lane = threadIdx.x & 63;
  const int row = blockIdx.x * 4 + wid;
  const unsigned short* xr = x + (size_t)row * DM_;

  unsigned int u[5];
  float s = 0.f, ss = 0.f;
#pragma unroll
  for (int i = 0; i < 5; ++i) {
    u[i] = *(const unsigned int*)(xr + 2 * (lane + 64 * i));
    float a0 = bf2f((unsigned short)(u[i] & 0xffff));
    float a1 = bf2f((unsigned short)(u[i] >> 16));
    s += a0 + a1;
    ss += a0 * a0 + a1 * a1;
  }
#pragma unroll
  for (int d = 1; d < 64; d <<= 1) {
    s += __shfl_xor(s, d);
    ss += __shfl_xor(ss, d);
  }
  const float mu = s * (1.f / 640.f);
  const float var = ss * (1.f / 640.f) - mu * mu;
  const float rstd = rsqrtf(var + 1e-5f);

  float* yr = y + (size_t)row * DM_;
#pragma unroll
  for (int i = 0; i < 5; ++i) {
    int c0 = 2 * (lane + 64 * i);
    float a0 = bf2f((unsigned short)(u[i] & 0xffff));
    float a1 = bf2f((unsigned short)(u[i] >> 16));
    float2 wv = *(const float2*)(lw + c0);
    float2 bv = *(const float2*)(lb + c0);
    float2 out;
    out.x = (a0 - mu) * rstd * wv.x + bv.x;
    out.y = (a1 - mu) * rstd * wv.y + bv.y;
    *(float2*)(yr + c0) = out;
  }
}

extern "C" void kernel_launch(void* const* d_in, const int* in_sizes, int n_in,
                              void* d_out, int out_size, void* d_ws, size_t ws_size,
                              hipStream_t stream) {
  const float* q = (const float*)d_in[0];
  const float* k = (const float*)d_in[1];
  const float* v = (const float*)d_in[2];
  const float* fw = (const float*)d_in[3];
  const float* fb = (const float*)d_in[4];
  const float* g1 = (const float*)d_in[5];
  const float* lw = (const float*)d_in[6];
  const float* lb = (const float*)d_in[7];

  unsigned short* vtp = (unsigned short*)d_out;                   // 10.62 MB V' tiles
  unsigned char* attn8 = (unsigned char*)d_out + ATTN8_OFF;       // 5.24 MB fp8 attn
  unsigned short* kp = (unsigned short*)d_ws;                     // 10.49 MB Kp
  unsigned short* xws = (unsigned short*)d_ws;                    // x overwrites Kp
  float* y = (float*)d_out;                                        // final overwrite

  prep_kernel<<<dim3(64 * 16), dim3(256), 0, stream>>>(k, v, kp, vtp);
  attn_kernel<<<dim3(64 * 8), dim3(256), 0, stream>>>(q, kp, vtp, attn8);
  fc_kernel<<<dim3(128 * 10), dim3(256), 0, stream>>>(attn8, fw, fb, g1, q, xws);
  ln_kernel<<<dim3(8192 / 4), dim3(256), 0, stream>>>(xws, lw, lb, y);
}